// Round 16
// baseline (164.125 us; speedup 1.0000x reference)
//
#include <hip/hip_runtime.h>
#include <hip/hip_cooperative_groups.h>
#include <math.h>

#define PATCH 16
#define BATCH 64
#define CIN 3
#define HH 224
#define WW 224
#define NPATCH (BATCH*14*14)       // 12544
#define KDIM 768
#define NOFF 512
#define NOUT 768
#define KPTS 256
#define EPSF 1e-5f
#define CHW (CIN*HH*WW)            // 150528
#define HWX (HH*WW)                // 50176
#define NRB (NPATCH/128)           // 98

using short8 = __attribute__((ext_vector_type(8))) short;
using f32x4  = __attribute__((ext_vector_type(4))) float;

#define GLOAD16(g, l) __builtin_amdgcn_global_load_lds( \
    (const __attribute__((address_space(1))) void*)(g), \
    (__attribute__((address_space(3))) void*)(l), 16, 0, 0)

__device__ __forceinline__ unsigned short f2bf(float f) {
    unsigned int u = __float_as_uint(f);
    u = (u + 0x7fffu + ((u >> 16) & 1u)) >> 16;   // RNE
    return (unsigned short)u;
}
__device__ __forceinline__ float bf2f(unsigned short h) {
    return __uint_as_float(((unsigned int)h) << 16);
}
__device__ __forceinline__ float gelu_exact(float v) {
    return 0.5f * v * (1.0f + erff(v * 0.70710678118654752440f));
}

// ---------------------------------------------------------------------------
// fused fp32 -> bf16 bulk convert for x, offw, dconvw (one launch) [R13]
// ---------------------------------------------------------------------------
#define N4X (BATCH*CHW/4)
#define N4W1 (NOFF*KDIM/4)
#define N4W2 (NOUT*KDIM/4)
#define N4ALL (N4X+N4W1+N4W2)

__global__ __launch_bounds__(256) void cvt_all(
    const float* __restrict__ x, const float* __restrict__ w1,
    const float* __restrict__ w2, unsigned short* __restrict__ xbf,
    unsigned short* __restrict__ wbf1, unsigned short* __restrict__ wbf2)
{
    for (int i = blockIdx.x*256 + threadIdx.x; i < N4ALL; i += gridDim.x*256) {
        const float* src; unsigned short* dst; int j;
        if (i < N4X)            { src = x;  dst = xbf;  j = i; }
        else if (i < N4X+N4W1)  { src = w1; dst = wbf1; j = i - N4X; }
        else                    { src = w2; dst = wbf2; j = i - N4X - N4W1; }
        float4 v = ((const float4*)src)[j];
        ((ushort4*)dst)[j] = make_ushort4(f2bf(v.x), f2bf(v.y), f2bf(v.z), f2bf(v.w));
    }
}

// ---------------------------------------------------------------------------
// GEMM1 [exact R13/R7]: depth-3 pipelined, 4 LDS slots, scalar bias epilogue
// ---------------------------------------------------------------------------
__global__ __launch_bounds__(256) void gemm_offsets(
    const unsigned short* __restrict__ xbf, const unsigned short* __restrict__ Bw,
    const float* __restrict__ offb, unsigned short* __restrict__ off)
{
    __shared__ unsigned short lds[4*8192];
    const int t = threadIdx.x;
    const int lane = t & 63;
    const int w = t >> 6, wr = w >> 1, wc = w & 1;

    int bid = blockIdx.x;                       // 392 = 8*49
    int idx = (bid & 7)*49 + (bid >> 3);
    const int bm = (idx >> 2) * 128, bn = (idx & 3) * 128;

    const int rq = t >> 2;
    const int ksw = (((t & 3) ^ ((t >> 3) & 3)) << 3);

    const unsigned short* aBase0;
    const unsigned short* aBase1;
    {
        int p0 = bm + rq,      b0 = p0/196, r0 = p0%196;
        int p1 = bm + 64 + rq, b1 = p1/196, r1 = p1%196;
        aBase0 = xbf + (size_t)b0*CHW + (size_t)((r0/14)*PATCH)*WW + (size_t)((r0%14)*PATCH);
        aBase1 = xbf + (size_t)b1*CHW + (size_t)((r1/14)*PATCH)*WW + (size_t)((r1%14)*PATCH);
    }
    const unsigned short* bS0 = Bw + (size_t)(bn + rq)*KDIM + ksw;
    const unsigned short* bS1 = Bw + (size_t)(bn + 64 + rq)*KDIM + ksw;

    const int row_a = wr*64 + (lane & 15);
    const int row_b = wc*64 + (lane & 15);
    const int klocs = (((lane >> 4) ^ ((lane >> 1) & 3)) << 3);

#define STG1(slot, k0) do { \
        unsigned short* d = lds + (slot)*8192 + t*8; \
        int e = (k0) + ksw; \
        size_t xo = (size_t)(e >> 8)*HWX + (size_t)((e >> 4) & 15)*WW + (e & 15); \
        GLOAD16(aBase0 + xo, d); \
        GLOAD16(aBase1 + xo, d + 2048); \
        GLOAD16(bS0 + (k0), d + 4096); \
        GLOAD16(bS1 + (k0), d + 6144); \
    } while(0)

    f32x4 acc[4][4] = {};
    STG1(0, 0); STG1(1, 32); STG1(2, 64);
    asm volatile("s_waitcnt vmcnt(8)" ::: "memory");
    __builtin_amdgcn_s_barrier();
#pragma unroll
    for (int it = 0; it < 24; ++it) {
        if (it + 3 < 24) STG1((it+3)&3, (it+3)*32);
        const unsigned short* As_ = lds + (it&3)*8192;
        const unsigned short* Bs_ = As_ + 4096;
        short8 af[4], bv[4];
#pragma unroll
        for (int m = 0; m < 4; ++m) af[m] = *(const short8*)&As_[(row_a + m*16)*32 + klocs];
#pragma unroll
        for (int n = 0; n < 4; ++n) bv[n] = *(const short8*)&Bs_[(row_b + n*16)*32 + klocs];
        __builtin_amdgcn_s_setprio(1);
#pragma unroll
        for (int m = 0; m < 4; ++m)
#pragma unroll
            for (int n = 0; n < 4; ++n)
                acc[m][n] = __builtin_amdgcn_mfma_f32_16x16x32_bf16(af[m], bv[n], acc[m][n], 0, 0, 0);
        __builtin_amdgcn_s_setprio(0);
        if (it <= 20)      { asm volatile("s_waitcnt vmcnt(8) lgkmcnt(0)" ::: "memory"); __builtin_amdgcn_s_barrier(); }
        else if (it == 21) { asm volatile("s_waitcnt vmcnt(4) lgkmcnt(0)" ::: "memory"); __builtin_amdgcn_s_barrier(); }
        else if (it == 22) { asm volatile("s_waitcnt vmcnt(0) lgkmcnt(0)" ::: "memory"); __builtin_amdgcn_s_barrier(); }
    }
#undef STG1

    const int col0 = bn + wc*64 + (lane & 15);
    const int r0 = (lane >> 4) * 4;
#pragma unroll
    for (int m = 0; m < 4; ++m) {
        int grow = bm + wr*64 + m*16 + r0;
#pragma unroll
        for (int n = 0; n < 4; ++n) {
            int gcol = col0 + n*16;
            float bias = offb[gcol];
#pragma unroll
            for (int r = 0; r < 4; ++r)
                off[(size_t)(grow + r)*NOFF + gcol] = f2bf(acc[m][n][r] + bias);
        }
    }
}

// ---------------------------------------------------------------------------
// Sampler [exact R13/R7]: LDS-staged 22x22 bf16 window; exact global fallback
// ---------------------------------------------------------------------------
__global__ __launch_bounds__(256) void sampler(
    const unsigned short* __restrict__ xbf, const unsigned int* __restrict__ offu,
    unsigned short* __restrict__ A2)
{
    __shared__ unsigned short win[3][22][24];
    int p = blockIdx.x;
    int k = threadIdx.x;
    int b = p / 196, rem = p % 196;
    int ho = rem / 14, wo = rem % 14;
    const int gy0 = ho*PATCH - 2, gx0 = wo*PATCH - 2;
    const unsigned short* xb = xbf + (size_t)b*CHW;

    bool interior = (ho >= 1) && (ho <= 12) && (wo >= 1) && (wo <= 12);
    if (interior) {
        for (int idx = k; idx < 3*22*11; idx += 256) {
            int c = idx / 242, r2 = idx - c*242;
            int row = r2 / 11, u = r2 - row*11;
            const unsigned int* src = (const unsigned int*)
                (xb + (size_t)c*HWX + (size_t)(gy0+row)*WW + gx0);
            *(unsigned int*)&win[c][row][2*u] = src[u];
        }
    } else {
        for (int idx = k; idx < 3*22*22; idx += 256) {
            int c = idx / 484, r2 = idx - c*484;
            int row = r2 / 22, col = r2 - row*22;
            int gy = min(max(gy0+row, 0), HH-1);
            int gx = min(max(gx0+col, 0), WW-1);
            win[c][row][col] = xb[(size_t)c*HWX + (size_t)gy*WW + gx];
        }
    }
    __syncthreads();

    unsigned int d2 = offu[(size_t)p*KPTS + k];
    float dy = __uint_as_float((d2 & 0xffffu) << 16);
    float dx = __uint_as_float(d2 & 0xffff0000u);
    float py = (float)(ho*PATCH + (k >> 4)) + dy;
    float px = (float)(wo*PATCH + (k & 15)) + dx;
    float fy = floorf(py), fx = floorf(px);
    float wy1 = py - fy, wx1 = px - fx;
    float wy0 = 1.f - wy1, wx0 = 1.f - wx1;
    int y0 = (int)fy, x0 = (int)fx;
    int y1 = y0 + 1, x1 = x0 + 1;
    bool oky0 = (y0 >= 0) & (y0 < HH);
    bool oky1 = (y1 >= 0) & (y1 < HH);
    bool okx0 = (x0 >= 0) & (x0 < WW);
    bool okx1 = (x1 >= 0) & (x1 < WW);
    float w00 = wy0*wx0, w01 = wy0*wx1, w10 = wy1*wx0, w11 = wy1*wx1;

    int ry = y0 - gy0, rx = x0 - gx0;
    if (ry >= 0 && ry <= 20 && rx >= 0 && rx <= 20) {
        float m00 = oky0 && okx0 ? 1.f : 0.f;
        float m01 = oky0 && okx1 ? 1.f : 0.f;
        float m10 = oky1 && okx0 ? 1.f : 0.f;
        float m11 = oky1 && okx1 ? 1.f : 0.f;
#pragma unroll
        for (int c = 0; c < CIN; ++c) {
            float v00 = bf2f(win[c][ry  ][rx  ]) * m00;
            float v01 = bf2f(win[c][ry  ][rx+1]) * m01;
            float v10 = bf2f(win[c][ry+1][rx  ]) * m10;
            float v11 = bf2f(win[c][ry+1][rx+1]) * m11;
            float v = v00*w00 + v01*w01 + v10*w10 + v11*w11;
            A2[(size_t)p*KDIM + c*KPTS + k] = f2bf(v);
        }
    } else {
        int yc0 = min(max(y0, 0), HH-1), yc1 = min(max(y1, 0), HH-1);
        int xc0 = min(max(x0, 0), WW-1), xc1 = min(max(x1, 0), WW-1);
#pragma unroll
        for (int c = 0; c < CIN; ++c) {
            const unsigned short* xc = xb + (size_t)c*HWX;
            float v00 = (oky0 && okx0) ? bf2f(xc[(size_t)yc0*WW + xc0]) : 0.f;
            float v01 = (oky0 && okx1) ? bf2f(xc[(size_t)yc0*WW + xc1]) : 0.f;
            float v10 = (oky1 && okx0) ? bf2f(xc[(size_t)yc1*WW + xc0]) : 0.f;
            float v11 = (oky1 && okx1) ? bf2f(xc[(size_t)yc1*WW + xc1]) : 0.f;
            float v = v00*w00 + v01*w01 + v10*w10 + v11*w11;
            A2[(size_t)p*KDIM + c*KPTS + k] = f2bf(v);
        }
    }
}

// ---------------------------------------------------------------------------
// GEMM2 — 8-phase 256x256, single barrier/phase [R15-verified] + FUSED
// BN + GELU epilogue via cooperative grid sync:
//   psum/psq -> threadfence -> grid.sync -> per-block scale/shift from the
//   full 98x768 table -> apply to acc in registers -> fp32 store to d_out.
// Removes ybf (19.3MB w + 19.3MB r), bn_final and norm_gelu launches.
// ---------------------------------------------------------------------------
__global__ __launch_bounds__(512) void gemm_deform(
    const unsigned short* __restrict__ A, const unsigned short* __restrict__ Bw,
    float* __restrict__ out, float* __restrict__ psum, float* __restrict__ psq,
    const float* __restrict__ gamma, const float* __restrict__ beta)
{
    __shared__ unsigned short lds[4*16384];   // 131072 B
    const int t = threadIdx.x;
    const int lane = t & 63;
    const int w = t >> 6;
    const int wr = w >> 2, wc = w & 3;

    int bid = blockIdx.x;                     // 147 = 3*19 + 5*18
    int xcd = bid & 7, jj = bid >> 3;
    int idx = (xcd < 3) ? xcd*19 + jj : 57 + (xcd-3)*18 + jj;
    const int mblk = idx / 3;
    const int bm = mblk*256, bn = (idx % 3)*256;

    const int schunk = ((t & 3) ^ ((t >> 3) & 3)) << 3;
    const unsigned short* aSrc = A  + (size_t)(bm + (t >> 2))*KDIM + schunk;
    const unsigned short* bSrc = Bw + (size_t)(bn + (t >> 2))*KDIM + schunk;

#define STG_A(s, k0) do { \
        unsigned short* d = lds + (s)*16384 + t*8; \
        GLOAD16(aSrc + (k0), d); \
        GLOAD16(aSrc + (size_t)128*KDIM + (k0), d + 4096); } while(0)
#define STG_B(s, k0) do { \
        unsigned short* d = lds + (s)*16384 + 8192 + t*8; \
        GLOAD16(bSrc + (k0), d); \
        GLOAD16(bSrc + (size_t)128*KDIM + (k0), d + 4096); } while(0)

    const int klocs = (((lane >> 4) ^ ((lane >> 1) & 3)) << 3);
    const int arow0 = wr*128 + (lane & 15);
    const int brow0 = wc*64  + (lane & 15);

    f32x4 acc[8][4] = {};

    STG_A(0, 0);  STG_B(0, 0);
    STG_A(1, 32); STG_B(1, 32);
    asm volatile("s_waitcnt vmcnt(4)" ::: "memory");
    __builtin_amdgcn_s_barrier();

    short8 af[8], bv[4];
    for (int kt = 0; kt < 12; ++kt) {
        const int s0 = (2*kt) & 3;
        const int s1 = s0 + 1;
        const int s2 = (s0 + 2) & 3;
        const int s3 = (s0 + 3) & 3;
        const int k2 = (2*kt + 2) * 32;
        const int k3 = (2*kt + 3) * 32;
        const unsigned short* H0 = lds + s0*16384;
        const unsigned short* H1 = lds + s1*16384;

        // ---- phase 0
#pragma unroll
        for (int m = 0; m < 8; ++m) af[m] = *(const short8*)&H0[(arow0 + m*16)*32 + klocs];
        bv[0] = *(const short8*)&H0[8192 + (brow0 +  0)*32 + klocs];
        bv[1] = *(const short8*)&H0[8192 + (brow0 + 16)*32 + klocs];
        if (kt < 11) STG_A(s2, k2);
        __builtin_amdgcn_s_barrier();
        asm volatile("s_waitcnt lgkmcnt(0)" ::: "memory");
        __builtin_amdgcn_s_setprio(1);
#pragma unroll
        for (int m = 0; m < 8; ++m) {
            acc[m][0] = __builtin_amdgcn_mfma_f32_16x16x32_bf16(af[m], bv[0], acc[m][0], 0, 0, 0);
            acc[m][1] = __builtin_amdgcn_mfma_f32_16x16x32_bf16(af[m], bv[1], acc[m][1], 0, 0, 0);
        }
        __builtin_amdgcn_s_setprio(0);

        // ---- phase 1
        bv[2] = *(const short8*)&H0[8192 + (brow0 + 32)*32 + klocs];
        bv[3] = *(const short8*)&H0[8192 + (brow0 + 48)*32 + klocs];
        if (kt < 11) { STG_B(s2, k2);
            asm volatile("s_waitcnt vmcnt(4)" ::: "memory");
        } else {
            asm volatile("s_waitcnt vmcnt(0)" ::: "memory");
        }
        __builtin_amdgcn_s_barrier();
        asm volatile("s_waitcnt lgkmcnt(0)" ::: "memory");
        __builtin_amdgcn_s_setprio(1);
#pragma unroll
        for (int m = 0; m < 8; ++m) {
            acc[m][2] = __builtin_amdgcn_mfma_f32_16x16x32_bf16(af[m], bv[2], acc[m][2], 0, 0, 0);
            acc[m][3] = __builtin_amdgcn_mfma_f32_16x16x32_bf16(af[m], bv[3], acc[m][3], 0, 0, 0);
        }
        __builtin_amdgcn_s_setprio(0);

        // ---- phase 2
#pragma unroll
        for (int m = 0; m < 8; ++m) af[m] = *(const short8*)&H1[(arow0 + m*16)*32 + klocs];
        bv[0] = *(const short8*)&H1[8192 + (brow0 +  0)*32 + klocs];
        bv[1] = *(const short8*)&H1[8192 + (brow0 + 16)*32 + klocs];
        if (kt < 11) STG_A(s3, k3);
        __builtin_amdgcn_s_barrier();
        asm volatile("s_waitcnt lgkmcnt(0)" ::: "memory");
        __builtin_amdgcn_s_setprio(1);
#pragma unroll
        for (int m = 0; m < 8; ++m) {
            acc[m][0] = __builtin_amdgcn_mfma_f32_16x16x32_bf16(af[m], bv[0], acc[m][0], 0, 0, 0);
            acc[m][1] = __builtin_amdgcn_mfma_f32_16x16x32_bf16(af[m], bv[1], acc[m][1], 0, 0, 0);
        }
        __builtin_amdgcn_s_setprio(0);

        // ---- phase 3
        bv[2] = *(const short8*)&H1[8192 + (brow0 + 32)*32 + klocs];
        bv[3] = *(const short8*)&H1[8192 + (brow0 + 48)*32 + klocs];
        if (kt < 11) { STG_B(s3, k3);
            asm volatile("s_waitcnt vmcnt(4)" ::: "memory");
        }
        __builtin_amdgcn_s_barrier();
        asm volatile("s_waitcnt lgkmcnt(0)" ::: "memory");
        __builtin_amdgcn_s_setprio(1);
#pragma unroll
        for (int m = 0; m < 8; ++m) {
            acc[m][2] = __builtin_amdgcn_mfma_f32_16x16x32_bf16(af[m], bv[2], acc[m][2], 0, 0, 0);
            acc[m][3] = __builtin_amdgcn_mfma_f32_16x16x32_bf16(af[m], bv[3], acc[m][3], 0, 0, 0);
        }
        __builtin_amdgcn_s_setprio(0);
    }
#undef STG_A
#undef STG_B

    asm volatile("s_waitcnt lgkmcnt(0)" ::: "memory");

    // ---- per-block BN partials -> global psum/psq
    float s[4] = {}, q[4] = {};
#pragma unroll
    for (int m = 0; m < 8; ++m)
#pragma unroll
        for (int n = 0; n < 4; ++n)
#pragma unroll
            for (int r = 0; r < 4; ++r) {
                float v = acc[m][n][r];
                s[n] += v; q[n] += v*v;
            }
#pragma unroll
    for (int n = 0; n < 4; ++n) {
        s[n] += __shfl_xor(s[n], 16); q[n] += __shfl_xor(q[n], 16);
        s[n] += __shfl_xor(s[n], 32); q[n] += __shfl_xor(q[n], 32);
    }

    __syncthreads();
    float* redS = (float*)lds;        // [2][256]
    float* redQ = redS + 512;
    if (lane < 16) {
#pragma unroll
        for (int n = 0; n < 4; ++n) {
            redS[wr*256 + wc*64 + n*16 + lane] = s[n];
            redQ[wr*256 + wc*64 + n*16 + lane] = q[n];
        }
    }
    __syncthreads();
    {
        int half = t >> 8;
        int c = t & 255;
        psum[(size_t)(bm/128 + half)*NOUT + bn + c] = redS[half*256 + c];
        psq [(size_t)(bm/128 + half)*NOUT + bn + c] = redQ[half*256 + c];
    }

    // ---- grid-wide sync (cooperative), then per-block scale/shift
    __threadfence();
    cooperative_groups::this_grid().sync();

    float* ssc = (float*)lds;         // reuse LDS
    float* ssh = ssc + 256;
    if (t < 256) {
        float s2 = 0.f, q2 = 0.f;
        for (int i = 0; i < NRB; ++i) {
            s2 += psum[(size_t)i*NOUT + bn + t];
            q2 += psq [(size_t)i*NOUT + bn + t];
        }
        float mean = s2 * (1.0f/(float)NPATCH);
        float var  = q2 * (1.0f/(float)NPATCH) - mean*mean;
        float inv  = 1.0f / sqrtf(var + EPSF);
        float sc   = gamma[bn + t] * inv;
        ssc[t] = sc;
        ssh[t] = beta[bn + t] - mean*sc;
    }
    __syncthreads();

    // ---- apply BN + exact GELU to accumulators, store fp32 to d_out
    const int col0l = wc*64 + (lane & 15);    // local col 0..255
    const int r0 = (lane >> 4) * 4;
#pragma unroll
    for (int m = 0; m < 8; ++m) {
        int grow = bm + wr*128 + m*16 + r0;
#pragma unroll
        for (int n = 0; n < 4; ++n) {
            int cl = col0l + n*16;
            float sc = ssc[cl], sh = ssh[cl];
#pragma unroll
            for (int r = 0; r < 4; ++r)
                out[(size_t)(grow + r)*NOUT + bn + cl] = gelu_exact(acc[m][n][r]*sc + sh);
        }
    }
}

// ---------------------------------------------------------------------------
extern "C" void kernel_launch(void* const* d_in, const int* in_sizes, int n_in,
                              void* d_out, int out_size, void* d_ws, size_t ws_size,
                              hipStream_t stream)
{
    const float* x      = (const float*)d_in[0];
    const float* offw   = (const float*)d_in[1];
    const float* offb   = (const float*)d_in[2];
    const float* dconvw = (const float*)d_in[3];
    const float* gamma  = (const float*)d_in[4];
    const float* beta   = (const float*)d_in[5];
    float* out = (float*)d_out;

    const size_t NX  = (size_t)BATCH*CHW;
    const size_t NW1 = (size_t)NOFF*KDIM;
    const size_t NW2 = (size_t)NOUT*KDIM;

    unsigned short* xbf   = (unsigned short*)d_ws;
    unsigned short* wbf1  = xbf  + NX;
    unsigned short* wbf2  = wbf1 + NW1;
    unsigned short* A2    = wbf2 + NW2;
    unsigned short* off   = A2   + (size_t)NPATCH*KDIM;
    float* fscratch = (float*)(off + (size_t)NPATCH*NOFF);
    float* psum  = fscratch;
    float* psq   = psum + NRB*NOUT;

    cvt_all<<<4096, 256, 0, stream>>>(x, offw, dconvw, xbf, wbf1, wbf2);
    gemm_offsets<<<392, 256, 0, stream>>>(xbf, wbf1, offb, off);
    sampler<<<NPATCH, 256, 0, stream>>>(xbf, (const unsigned int*)off, A2);

    {
        const unsigned short* A2c = A2;
        const unsigned short* Wc  = wbf2;
        void* args[] = { (void*)&A2c, (void*)&Wc, (void*)&out,
                         (void*)&psum, (void*)&psq, (void*)&gamma, (void*)&beta };
        hipLaunchCooperativeKernel((const void*)gemm_deform, dim3(147), dim3(512),
                                   args, 0, stream);
    }
}

// Round 17
// 100.911 us; speedup vs baseline: 1.6264x; 1.6264x over previous
//
#include <hip/hip_runtime.h>
#include <math.h>

#define PATCH 16
#define BATCH 64
#define CIN 3
#define HH 224
#define WW 224
#define NPATCH (BATCH*14*14)       // 12544
#define KDIM 768
#define NOFF 512
#define NOUT 768
#define KPTS 256
#define EPSF 1e-5f
#define CHW (CIN*HH*WW)            // 150528
#define HWX (HH*WW)                // 50176
#define NRB (NPATCH/128)           // 98

using short8 = __attribute__((ext_vector_type(8))) short;
using f32x4  = __attribute__((ext_vector_type(4))) float;

#define GLOAD16(g, l) __builtin_amdgcn_global_load_lds( \
    (const __attribute__((address_space(1))) void*)(g), \
    (__attribute__((address_space(3))) void*)(l), 16, 0, 0)

__device__ __forceinline__ unsigned short f2bf(float f) {
    unsigned int u = __float_as_uint(f);
    u = (u + 0x7fffu + ((u >> 16) & 1u)) >> 16;   // RNE
    return (unsigned short)u;
}
__device__ __forceinline__ float bf2f(unsigned short h) {
    return __uint_as_float(((unsigned int)h) << 16);
}
__device__ __forceinline__ float gelu_exact(float v) {
    return 0.5f * v * (1.0f + erff(v * 0.70710678118654752440f));
}

// ---------------------------------------------------------------------------
// fused fp32 -> bf16 bulk convert for x, offw, dconvw (one launch) [R15]
// ---------------------------------------------------------------------------
#define N4X (BATCH*CHW/4)
#define N4W1 (NOFF*KDIM/4)
#define N4W2 (NOUT*KDIM/4)
#define N4ALL (N4X+N4W1+N4W2)

__global__ __launch_bounds__(256) void cvt_all(
    const float* __restrict__ x, const float* __restrict__ w1,
    const float* __restrict__ w2, unsigned short* __restrict__ xbf,
    unsigned short* __restrict__ wbf1, unsigned short* __restrict__ wbf2)
{
    for (int i = blockIdx.x*256 + threadIdx.x; i < N4ALL; i += gridDim.x*256) {
        const float* src; unsigned short* dst; int j;
        if (i < N4X)            { src = x;  dst = xbf;  j = i; }
        else if (i < N4X+N4W1)  { src = w1; dst = wbf1; j = i - N4X; }
        else                    { src = w2; dst = wbf2; j = i - N4X - N4W1; }
        float4 v = ((const float4*)src)[j];
        ((ushort4*)dst)[j] = make_ushort4(f2bf(v.x), f2bf(v.y), f2bf(v.z), f2bf(v.w));
    }
}

// ---------------------------------------------------------------------------
// GEMM1 [exact R15/R7]: depth-3 pipelined, 4 LDS slots, scalar bias epilogue
// ---------------------------------------------------------------------------
__global__ __launch_bounds__(256) void gemm_offsets(
    const unsigned short* __restrict__ xbf, const unsigned short* __restrict__ Bw,
    const float* __restrict__ offb, unsigned short* __restrict__ off)
{
    __shared__ unsigned short lds[4*8192];
    const int t = threadIdx.x;
    const int lane = t & 63;
    const int w = t >> 6, wr = w >> 1, wc = w & 1;

    int bid = blockIdx.x;                       // 392 = 8*49
    int idx = (bid & 7)*49 + (bid >> 3);
    const int bm = (idx >> 2) * 128, bn = (idx & 3) * 128;

    const int rq = t >> 2;
    const int ksw = (((t & 3) ^ ((t >> 3) & 3)) << 3);

    const unsigned short* aBase0;
    const unsigned short* aBase1;
    {
        int p0 = bm + rq,      b0 = p0/196, r0 = p0%196;
        int p1 = bm + 64 + rq, b1 = p1/196, r1 = p1%196;
        aBase0 = xbf + (size_t)b0*CHW + (size_t)((r0/14)*PATCH)*WW + (size_t)((r0%14)*PATCH);
        aBase1 = xbf + (size_t)b1*CHW + (size_t)((r1/14)*PATCH)*WW + (size_t)((r1%14)*PATCH);
    }
    const unsigned short* bS0 = Bw + (size_t)(bn + rq)*KDIM + ksw;
    const unsigned short* bS1 = Bw + (size_t)(bn + 64 + rq)*KDIM + ksw;

    const int row_a = wr*64 + (lane & 15);
    const int row_b = wc*64 + (lane & 15);
    const int klocs = (((lane >> 4) ^ ((lane >> 1) & 3)) << 3);

#define STG1(slot, k0) do { \
        unsigned short* d = lds + (slot)*8192 + t*8; \
        int e = (k0) + ksw; \
        size_t xo = (size_t)(e >> 8)*HWX + (size_t)((e >> 4) & 15)*WW + (e & 15); \
        GLOAD16(aBase0 + xo, d); \
        GLOAD16(aBase1 + xo, d + 2048); \
        GLOAD16(bS0 + (k0), d + 4096); \
        GLOAD16(bS1 + (k0), d + 6144); \
    } while(0)

    f32x4 acc[4][4] = {};
    STG1(0, 0); STG1(1, 32); STG1(2, 64);
    asm volatile("s_waitcnt vmcnt(8)" ::: "memory");
    __builtin_amdgcn_s_barrier();
#pragma unroll
    for (int it = 0; it < 24; ++it) {
        if (it + 3 < 24) STG1((it+3)&3, (it+3)*32);
        const unsigned short* As_ = lds + (it&3)*8192;
        const unsigned short* Bs_ = As_ + 4096;
        short8 af[4], bv[4];
#pragma unroll
        for (int m = 0; m < 4; ++m) af[m] = *(const short8*)&As_[(row_a + m*16)*32 + klocs];
#pragma unroll
        for (int n = 0; n < 4; ++n) bv[n] = *(const short8*)&Bs_[(row_b + n*16)*32 + klocs];
        __builtin_amdgcn_s_setprio(1);
#pragma unroll
        for (int m = 0; m < 4; ++m)
#pragma unroll
            for (int n = 0; n < 4; ++n)
                acc[m][n] = __builtin_amdgcn_mfma_f32_16x16x32_bf16(af[m], bv[n], acc[m][n], 0, 0, 0);
        __builtin_amdgcn_s_setprio(0);
        if (it <= 20)      { asm volatile("s_waitcnt vmcnt(8) lgkmcnt(0)" ::: "memory"); __builtin_amdgcn_s_barrier(); }
        else if (it == 21) { asm volatile("s_waitcnt vmcnt(4) lgkmcnt(0)" ::: "memory"); __builtin_amdgcn_s_barrier(); }
        else if (it == 22) { asm volatile("s_waitcnt vmcnt(0) lgkmcnt(0)" ::: "memory"); __builtin_amdgcn_s_barrier(); }
    }
#undef STG1

    const int col0 = bn + wc*64 + (lane & 15);
    const int r0 = (lane >> 4) * 4;
#pragma unroll
    for (int m = 0; m < 4; ++m) {
        int grow = bm + wr*64 + m*16 + r0;
#pragma unroll
        for (int n = 0; n < 4; ++n) {
            int gcol = col0 + n*16;
            float bias = offb[gcol];
#pragma unroll
            for (int r = 0; r < 4; ++r)
                off[(size_t)(grow + r)*NOFF + gcol] = f2bf(acc[m][n][r] + bias);
        }
    }
}

// ---------------------------------------------------------------------------
// Sampler [exact R15/R7]: LDS-staged 22x22 bf16 window; exact global fallback
// ---------------------------------------------------------------------------
__global__ __launch_bounds__(256) void sampler(
    const unsigned short* __restrict__ xbf, const unsigned int* __restrict__ offu,
    unsigned short* __restrict__ A2)
{
    __shared__ unsigned short win[3][22][24];
    int p = blockIdx.x;
    int k = threadIdx.x;
    int b = p / 196, rem = p % 196;
    int ho = rem / 14, wo = rem % 14;
    const int gy0 = ho*PATCH - 2, gx0 = wo*PATCH - 2;
    const unsigned short* xb = xbf + (size_t)b*CHW;

    bool interior = (ho >= 1) && (ho <= 12) && (wo >= 1) && (wo <= 12);
    if (interior) {
        for (int idx = k; idx < 3*22*11; idx += 256) {
            int c = idx / 242, r2 = idx - c*242;
            int row = r2 / 11, u = r2 - row*11;
            const unsigned int* src = (const unsigned int*)
                (xb + (size_t)c*HWX + (size_t)(gy0+row)*WW + gx0);
            *(unsigned int*)&win[c][row][2*u] = src[u];
        }
    } else {
        for (int idx = k; idx < 3*22*22; idx += 256) {
            int c = idx / 484, r2 = idx - c*484;
            int row = r2 / 22, col = r2 - row*22;
            int gy = min(max(gy0+row, 0), HH-1);
            int gx = min(max(gx0+col, 0), WW-1);
            win[c][row][col] = xb[(size_t)c*HWX + (size_t)gy*WW + gx];
        }
    }
    __syncthreads();

    unsigned int d2 = offu[(size_t)p*KPTS + k];
    float dy = __uint_as_float((d2 & 0xffffu) << 16);
    float dx = __uint_as_float(d2 & 0xffff0000u);
    float py = (float)(ho*PATCH + (k >> 4)) + dy;
    float px = (float)(wo*PATCH + (k & 15)) + dx;
    float fy = floorf(py), fx = floorf(px);
    float wy1 = py - fy, wx1 = px - fx;
    float wy0 = 1.f - wy1, wx0 = 1.f - wx1;
    int y0 = (int)fy, x0 = (int)fx;
    int y1 = y0 + 1, x1 = x0 + 1;
    bool oky0 = (y0 >= 0) & (y0 < HH);
    bool oky1 = (y1 >= 0) & (y1 < HH);
    bool okx0 = (x0 >= 0) & (x0 < WW);
    bool okx1 = (x1 >= 0) & (x1 < WW);
    float w00 = wy0*wx0, w01 = wy0*wx1, w10 = wy1*wx0, w11 = wy1*wx1;

    int ry = y0 - gy0, rx = x0 - gx0;
    if (ry >= 0 && ry <= 20 && rx >= 0 && rx <= 20) {
        float m00 = oky0 && okx0 ? 1.f : 0.f;
        float m01 = oky0 && okx1 ? 1.f : 0.f;
        float m10 = oky1 && okx0 ? 1.f : 0.f;
        float m11 = oky1 && okx1 ? 1.f : 0.f;
#pragma unroll
        for (int c = 0; c < CIN; ++c) {
            float v00 = bf2f(win[c][ry  ][rx  ]) * m00;
            float v01 = bf2f(win[c][ry  ][rx+1]) * m01;
            float v10 = bf2f(win[c][ry+1][rx  ]) * m10;
            float v11 = bf2f(win[c][ry+1][rx+1]) * m11;
            float v = v00*w00 + v01*w01 + v10*w10 + v11*w11;
            A2[(size_t)p*KDIM + c*KPTS + k] = f2bf(v);
        }
    } else {
        int yc0 = min(max(y0, 0), HH-1), yc1 = min(max(y1, 0), HH-1);
        int xc0 = min(max(x0, 0), WW-1), xc1 = min(max(x1, 0), WW-1);
#pragma unroll
        for (int c = 0; c < CIN; ++c) {
            const unsigned short* xc = xb + (size_t)c*HWX;
            float v00 = (oky0 && okx0) ? bf2f(xc[(size_t)yc0*WW + xc0]) : 0.f;
            float v01 = (oky0 && okx1) ? bf2f(xc[(size_t)yc0*WW + xc1]) : 0.f;
            float v10 = (oky1 && okx0) ? bf2f(xc[(size_t)yc1*WW + xc0]) : 0.f;
            float v11 = (oky1 && okx1) ? bf2f(xc[(size_t)yc1*WW + xc1]) : 0.f;
            float v = v00*w00 + v01*w01 + v10*w10 + v11*w11;
            A2[(size_t)p*KDIM + c*KPTS + k] = f2bf(v);
        }
    }
}

// ---------------------------------------------------------------------------
// GEMM2 — 8-phase 256x256 ring, now 2 phases per kt (one full 32-k half per
// phase: 12 ds_read_b128 + stage A+B of a future half (4 ops) + vmcnt(4) +
// barrier + lgkmcnt(0) + 32 MFMA). Ledger: phase A publishes half 2t+1,
// phase B publishes half 2t+2; slot overwrite distance = 2 barriers past the
// lgkmcnt(0) that drained its readers. ybf out + fused BN partials [R15].
// ---------------------------------------------------------------------------
__global__ __launch_bounds__(512) void gemm_deform(
    const unsigned short* __restrict__ A, const unsigned short* __restrict__ Bw,
    unsigned short* __restrict__ Cbf, float* __restrict__ psum, float* __restrict__ psq)
{
    __shared__ unsigned short lds[4*16384];   // 131072 B
    const int t = threadIdx.x;
    const int lane = t & 63;
    const int w = t >> 6;
    const int wr = w >> 2, wc = w & 3;

    int bid = blockIdx.x;                     // 147 = 3*19 + 5*18
    int xcd = bid & 7, jj = bid >> 3;
    int idx = (xcd < 3) ? xcd*19 + jj : 57 + (xcd-3)*18 + jj;
    const int mblk = idx / 3;
    const int bm = mblk*256, bn = (idx % 3)*256;

    const int schunk = ((t & 3) ^ ((t >> 3) & 3)) << 3;
    const unsigned short* aSrc = A  + (size_t)(bm + (t >> 2))*KDIM + schunk;
    const unsigned short* bSrc = Bw + (size_t)(bn + (t >> 2))*KDIM + schunk;

#define STG_A(s, k0) do { \
        unsigned short* d = lds + (s)*16384 + t*8; \
        GLOAD16(aSrc + (k0), d); \
        GLOAD16(aSrc + (size_t)128*KDIM + (k0), d + 4096); } while(0)
#define STG_B(s, k0) do { \
        unsigned short* d = lds + (s)*16384 + 8192 + t*8; \
        GLOAD16(bSrc + (k0), d); \
        GLOAD16(bSrc + (size_t)128*KDIM + (k0), d + 4096); } while(0)

    const int klocs = (((lane >> 4) ^ ((lane >> 1) & 3)) << 3);
    const int arow0 = wr*128 + (lane & 15);
    const int brow0 = wc*64  + (lane & 15);

    f32x4 acc[8][4] = {};

    STG_A(0, 0);  STG_B(0, 0);
    STG_A(1, 32); STG_B(1, 32);
    asm volatile("s_waitcnt vmcnt(4)" ::: "memory");   // half 0 published
    __builtin_amdgcn_s_barrier();

    short8 af[8], bv[4];
    for (int kt = 0; kt < 12; ++kt) {
        const int s0 = (2*kt) & 3;
        const int s1 = s0 + 1;
        const int s2 = (s0 + 2) & 3;
        const int s3 = (s0 + 3) & 3;
        const int k2 = (2*kt + 2) * 32;
        const int k3 = (2*kt + 3) * 32;
        const unsigned short* H0 = lds + s0*16384;
        const unsigned short* H1 = lds + s1*16384;

        // ---- phase A: compute half s0; stage half 2t+2 (A+B)
#pragma unroll
        for (int m = 0; m < 8; ++m) af[m] = *(const short8*)&H0[(arow0 + m*16)*32 + klocs];
#pragma unroll
        for (int n = 0; n < 4; ++n) bv[n] = *(const short8*)&H0[8192 + (brow0 + n*16)*32 + klocs];
        if (kt < 11) { STG_A(s2, k2); STG_B(s2, k2);
            asm volatile("s_waitcnt vmcnt(4)" ::: "memory");   // half 2t+1 ready
        } else {
            asm volatile("s_waitcnt vmcnt(0)" ::: "memory");
        }
        __builtin_amdgcn_s_barrier();
        asm volatile("s_waitcnt lgkmcnt(0)" ::: "memory");
        __builtin_amdgcn_s_setprio(1);
#pragma unroll
        for (int m = 0; m < 8; ++m)
#pragma unroll
            for (int n = 0; n < 4; ++n)
                acc[m][n] = __builtin_amdgcn_mfma_f32_16x16x32_bf16(af[m], bv[n], acc[m][n], 0, 0, 0);
        __builtin_amdgcn_s_setprio(0);

        // ---- phase B: compute half s1; stage half 2t+3 (A+B)
#pragma unroll
        for (int m = 0; m < 8; ++m) af[m] = *(const short8*)&H1[(arow0 + m*16)*32 + klocs];
#pragma unroll
        for (int n = 0; n < 4; ++n) bv[n] = *(const short8*)&H1[8192 + (brow0 + n*16)*32 + klocs];
        if (kt < 11) { STG_A(s3, k3); STG_B(s3, k3);
            asm volatile("s_waitcnt vmcnt(4)" ::: "memory");   // half 2t+2 ready
        }
        __builtin_amdgcn_s_barrier();
        asm volatile("s_waitcnt lgkmcnt(0)" ::: "memory");
        __builtin_amdgcn_s_setprio(1);
#pragma unroll
        for (int m = 0; m < 8; ++m)
#pragma unroll
            for (int n = 0; n < 4; ++n)
                acc[m][n] = __builtin_amdgcn_mfma_f32_16x16x32_bf16(af[m], bv[n], acc[m][n], 0, 0, 0);
        __builtin_amdgcn_s_setprio(0);
    }
#undef STG_A
#undef STG_B

    asm volatile("s_waitcnt lgkmcnt(0)" ::: "memory");

    // BN per-thread column partials, reduce over lane bits 4,5
    float s[4] = {}, q[4] = {};
#pragma unroll
    for (int m = 0; m < 8; ++m)
#pragma unroll
        for (int n = 0; n < 4; ++n)
#pragma unroll
            for (int r = 0; r < 4; ++r) {
                float v = acc[m][n][r];
                s[n] += v; q[n] += v*v;
            }
#pragma unroll
    for (int n = 0; n < 4; ++n) {
        s[n] += __shfl_xor(s[n], 16); q[n] += __shfl_xor(q[n], 16);
        s[n] += __shfl_xor(s[n], 32); q[n] += __shfl_xor(q[n], 32);
    }

    __syncthreads();
    float* redS = (float*)lds;        // [2][256]
    float* redQ = redS + 512;
    if (lane < 16) {
#pragma unroll
        for (int n = 0; n < 4; ++n) {
            redS[wr*256 + wc*64 + n*16 + lane] = s[n];
            redQ[wr*256 + wc*64 + n*16 + lane] = q[n];
        }
    }
    __syncthreads();

    const int col0 = bn + wc*64 + (lane & 15);
    const int r0 = (lane >> 4) * 4;
#pragma unroll
    for (int m = 0; m < 8; ++m) {
        int grow = bm + wr*128 + m*16 + r0;
#pragma unroll
        for (int n = 0; n < 4; ++n) {
            int gcol = col0 + n*16;
#pragma unroll
            for (int r = 0; r < 4; ++r)
                Cbf[(size_t)(grow + r)*NOUT + gcol] = f2bf(acc[m][n][r]);
        }
    }
    {
        int half = t >> 8;
        int c = t & 255;
        psum[(size_t)(bm/128 + half)*NOUT + bn + c] = redS[half*256 + c];
        psq [(size_t)(bm/128 + half)*NOUT + bn + c] = redQ[half*256 + c];
    }
}

// ---------------------------------------------------------------------------
__global__ __launch_bounds__(256) void bn_final(
    const float* __restrict__ psum, const float* __restrict__ psq,
    const float* __restrict__ gamma, const float* __restrict__ beta,
    float* __restrict__ scale, float* __restrict__ shift)
{
    int o = blockIdx.x*256 + threadIdx.x;
    float s = 0.f, q = 0.f;
    for (int i = 0; i < NRB; ++i) {
        s += psum[(size_t)i*NOUT + o];
        q += psq [(size_t)i*NOUT + o];
    }
    float mean = s * (1.0f/(float)NPATCH);
    float var  = q * (1.0f/(float)NPATCH) - mean*mean;
    float inv  = 1.0f / sqrtf(var + EPSF);
    float sc   = gamma[o] * inv;
    scale[o] = sc;
    shift[o] = beta[o] - mean*sc;
}

// ---------------------------------------------------------------------------
__global__ __launch_bounds__(256) void norm_gelu(
    const unsigned short* __restrict__ ybf, float* __restrict__ out,
    const float* __restrict__ scale, const float* __restrict__ shift)
{
    __shared__ float ssc[NOUT], ssh[NOUT];
    for (int i = threadIdx.x; i < NOUT; i += 256) { ssc[i] = scale[i]; ssh[i] = shift[i]; }
    __syncthreads();
    const size_t total8 = (size_t)NPATCH * NOUT / 8;
    for (size_t i = (size_t)blockIdx.x*256 + threadIdx.x; i < total8;
         i += (size_t)gridDim.x*256) {
        uint4 v = ((const uint4*)ybf)[i];
        int og = (int)(i % (NOUT/8)) * 8;
        float4 o0, o1;
        o0.x = gelu_exact(__uint_as_float(v.x << 16)        * ssc[og+0] + ssh[og+0]);
        o0.y = gelu_exact(__uint_as_float(v.x & 0xffff0000u)* ssc[og+1] + ssh[og+1]);
        o0.z = gelu_exact(__uint_as_float(v.y << 16)        * ssc[og+2] + ssh[og+2]);
        o0.w = gelu_exact(__uint_as_float(v.y & 0xffff0000u)* ssc[og+3] + ssh[og+3]);
        o1.x = gelu_exact(__uint_as_float(v.z << 16)        * ssc[og+4] + ssh[og+4]);
        o1.y = gelu_exact(__uint_as_float(v.z & 0xffff0000u)* ssc[og+5] + ssh[og+5]);
        o1.z = gelu_exact(__uint_as_float(v.w << 16)        * ssc[og+6] + ssh[og+6]);
        o1.w = gelu_exact(__uint_as_float(v.w & 0xffff0000u)* ssc[og+7] + ssh[og+7]);
        ((float4*)out)[2*i]   = o0;
        ((float4*)out)[2*i+1] = o1;
    }
}

// ---------------------------------------------------------------------------
extern "C" void kernel_launch(void* const* d_in, const int* in_sizes, int n_in,
                              void* d_out, int out_size, void* d_ws, size_t ws_size,
                              hipStream_t stream)
{
    const float* x      = (const float*)d_in[0];
    const float* offw   = (const float*)d_in[1];
    const float* offb   = (const float*)d_in[2];
    const float* dconvw = (const float*)d_in[3];
    const float* gamma  = (const float*)d_in[4];
    const float* beta   = (const float*)d_in[5];
    float* out = (float*)d_out;

    const size_t NX  = (size_t)BATCH*CHW;
    const size_t NW1 = (size_t)NOFF*KDIM;
    const size_t NW2 = (size_t)NOUT*KDIM;

    unsigned short* xbf   = (unsigned short*)d_ws;
    unsigned short* wbf1  = xbf  + NX;
    unsigned short* wbf2  = wbf1 + NW1;
    unsigned short* A2    = wbf2 + NW2;
    unsigned short* off   = A2   + (size_t)NPATCH*KDIM;
    unsigned short* ybf   = off  + (size_t)NPATCH*NOFF;
    float* fscratch = (float*)(ybf + (size_t)NPATCH*NOUT);
    float* psum  = fscratch;
    float* psq   = psum + NRB*NOUT;
    float* scale = psq  + NRB*NOUT;
    float* shift = scale + NOUT;

    cvt_all<<<4096, 256, 0, stream>>>(x, offw, dconvw, xbf, wbf1, wbf2);
    gemm_offsets<<<392, 256, 0, stream>>>(xbf, wbf1, offb, off);
    sampler<<<NPATCH, 256, 0, stream>>>(xbf, (const unsigned int*)off, A2);
    gemm_deform<<<147, 512, 0, stream>>>(A2, wbf2, ybf, psum, psq);
    bn_final<<<3, 256, 0, stream>>>(psum, psq, gamma, beta, scale, shift);
    norm_gelu<<<2048, 256, 0, stream>>>(ybf, out, scale, shift);
}

// Round 18
// 100.134 us; speedup vs baseline: 1.6391x; 1.0078x over previous
//
#include <hip/hip_runtime.h>
#include <math.h>

#define PATCH 16
#define BATCH 64
#define CIN 3
#define HH 224
#define WW 224
#define NPATCH (BATCH*14*14)       // 12544
#define KDIM 768
#define NOFF 512
#define NOUT 768
#define KPTS 256
#define EPSF 1e-5f
#define CHW (CIN*HH*WW)            // 150528
#define HWX (HH*WW)                // 50176
#define NRB (NPATCH/128)           // 98

using short8 = __attribute__((ext_vector_type(8))) short;
using f32x4  = __attribute__((ext_vector_type(4))) float;

#define GLOAD16(g, l) __builtin_amdgcn_global_load_lds( \
    (const __attribute__((address_space(1))) void*)(g), \
    (__attribute__((address_space(3))) void*)(l), 16, 0, 0)

__device__ __forceinline__ unsigned short f2bf(float f) {
    unsigned int u = __float_as_uint(f);
    u = (u + 0x7fffu + ((u >> 16) & 1u)) >> 16;   // RNE
    return (unsigned short)u;
}
__device__ __forceinline__ float bf2f(unsigned short h) {
    return __uint_as_float(((unsigned int)h) << 16);
}
__device__ __forceinline__ float gelu_exact(float v) {
    return 0.5f * v * (1.0f + erff(v * 0.70710678118654752440f));
}

// ---------------------------------------------------------------------------
// fused fp32 -> bf16 bulk convert for x, offw, dconvw (one launch) [R15]
// ---------------------------------------------------------------------------
#define N4X (BATCH*CHW/4)
#define N4W1 (NOFF*KDIM/4)
#define N4W2 (NOUT*KDIM/4)
#define N4ALL (N4X+N4W1+N4W2)

__global__ __launch_bounds__(256) void cvt_all(
    const float* __restrict__ x, const float* __restrict__ w1,
    const float* __restrict__ w2, unsigned short* __restrict__ xbf,
    unsigned short* __restrict__ wbf1, unsigned short* __restrict__ wbf2)
{
    for (int i = blockIdx.x*256 + threadIdx.x; i < N4ALL; i += gridDim.x*256) {
        const float* src; unsigned short* dst; int j;
        if (i < N4X)            { src = x;  dst = xbf;  j = i; }
        else if (i < N4X+N4W1)  { src = w1; dst = wbf1; j = i - N4X; }
        else                    { src = w2; dst = wbf2; j = i - N4X - N4W1; }
        float4 v = ((const float4*)src)[j];
        ((ushort4*)dst)[j] = make_ushort4(f2bf(v.x), f2bf(v.y), f2bf(v.z), f2bf(v.w));
    }
}

// ---------------------------------------------------------------------------
// GEMM1 — single barrier per iteration, 5-slot ring (80KB), prefetch depth 3.
// Overwrite safety: STG at it targets slot holding half it-2, whose readers
// drained at lgkmcnt(0) two barriers earlier (distance-2, R15-proof shape).
// vmcnt: steady 8 (h_{it+1} complete for next phase's pre-barrier reads);
// epilogue 8/4/0 at it=20/21/22; it=23 barrier-free.
// ---------------------------------------------------------------------------
__global__ __launch_bounds__(256) void gemm_offsets(
    const unsigned short* __restrict__ xbf, const unsigned short* __restrict__ Bw,
    const float* __restrict__ offb, unsigned short* __restrict__ off)
{
    __shared__ unsigned short lds[5*8192];
    const int t = threadIdx.x;
    const int lane = t & 63;
    const int w = t >> 6, wr = w >> 1, wc = w & 1;

    int bid = blockIdx.x;                       // 392 = 8*49
    int idx = (bid & 7)*49 + (bid >> 3);
    const int bm = (idx >> 2) * 128, bn = (idx & 3) * 128;

    const int rq = t >> 2;
    const int ksw = (((t & 3) ^ ((t >> 3) & 3)) << 3);

    const unsigned short* aBase0;
    const unsigned short* aBase1;
    {
        int p0 = bm + rq,      b0 = p0/196, r0 = p0%196;
        int p1 = bm + 64 + rq, b1 = p1/196, r1 = p1%196;
        aBase0 = xbf + (size_t)b0*CHW + (size_t)((r0/14)*PATCH)*WW + (size_t)((r0%14)*PATCH);
        aBase1 = xbf + (size_t)b1*CHW + (size_t)((r1/14)*PATCH)*WW + (size_t)((r1%14)*PATCH);
    }
    const unsigned short* bS0 = Bw + (size_t)(bn + rq)*KDIM + ksw;
    const unsigned short* bS1 = Bw + (size_t)(bn + 64 + rq)*KDIM + ksw;

    const int row_a = wr*64 + (lane & 15);
    const int row_b = wc*64 + (lane & 15);
    const int klocs = (((lane >> 4) ^ ((lane >> 1) & 3)) << 3);

#define STG1(slot, k0) do { \
        unsigned short* d = lds + (slot)*8192 + t*8; \
        int e = (k0) + ksw; \
        size_t xo = (size_t)(e >> 8)*HWX + (size_t)((e >> 4) & 15)*WW + (e & 15); \
        GLOAD16(aBase0 + xo, d); \
        GLOAD16(aBase1 + xo, d + 2048); \
        GLOAD16(bS0 + (k0), d + 4096); \
        GLOAD16(bS1 + (k0), d + 6144); \
    } while(0)

    f32x4 acc[4][4] = {};
    STG1(0, 0); STG1(1, 32); STG1(2, 64);
    asm volatile("s_waitcnt vmcnt(8)" ::: "memory");   // h0 complete
    __builtin_amdgcn_s_barrier();
#pragma unroll
    for (int it = 0; it < 24; ++it) {
        const unsigned short* As_ = lds + (it%5)*8192;
        const unsigned short* Bs_ = As_ + 4096;
        short8 af[4], bv[4];
#pragma unroll
        for (int m = 0; m < 4; ++m) af[m] = *(const short8*)&As_[(row_a + m*16)*32 + klocs];
#pragma unroll
        for (int n = 0; n < 4; ++n) bv[n] = *(const short8*)&Bs_[(row_b + n*16)*32 + klocs];
        if (it + 3 < 24) STG1((it+3)%5, (it+3)*32);
        if (it < 23) {
            if (it <= 20)      asm volatile("s_waitcnt vmcnt(8)" ::: "memory");
            else if (it == 21) asm volatile("s_waitcnt vmcnt(4)" ::: "memory");
            else               asm volatile("s_waitcnt vmcnt(0)" ::: "memory");
            __builtin_amdgcn_s_barrier();
        }
        asm volatile("s_waitcnt lgkmcnt(0)" ::: "memory");
        __builtin_amdgcn_s_setprio(1);
#pragma unroll
        for (int m = 0; m < 4; ++m)
#pragma unroll
            for (int n = 0; n < 4; ++n)
                acc[m][n] = __builtin_amdgcn_mfma_f32_16x16x32_bf16(af[m], bv[n], acc[m][n], 0, 0, 0);
        __builtin_amdgcn_s_setprio(0);
    }
#undef STG1

    const int col0 = bn + wc*64 + (lane & 15);
    const int r0 = (lane >> 4) * 4;
#pragma unroll
    for (int m = 0; m < 4; ++m) {
        int grow = bm + wr*64 + m*16 + r0;
#pragma unroll
        for (int n = 0; n < 4; ++n) {
            int gcol = col0 + n*16;
            float bias = offb[gcol];
#pragma unroll
            for (int r = 0; r < 4; ++r)
                off[(size_t)(grow + r)*NOFF + gcol] = f2bf(acc[m][n][r] + bias);
        }
    }
}

// ---------------------------------------------------------------------------
// Sampler [exact R15/R7]: LDS-staged 22x22 bf16 window; exact global fallback
// ---------------------------------------------------------------------------
__global__ __launch_bounds__(256) void sampler(
    const unsigned short* __restrict__ xbf, const unsigned int* __restrict__ offu,
    unsigned short* __restrict__ A2)
{
    __shared__ unsigned short win[3][22][24];
    int p = blockIdx.x;
    int k = threadIdx.x;
    int b = p / 196, rem = p % 196;
    int ho = rem / 14, wo = rem % 14;
    const int gy0 = ho*PATCH - 2, gx0 = wo*PATCH - 2;
    const unsigned short* xb = xbf + (size_t)b*CHW;

    bool interior = (ho >= 1) && (ho <= 12) && (wo >= 1) && (wo <= 12);
    if (interior) {
        for (int idx = k; idx < 3*22*11; idx += 256) {
            int c = idx / 242, r2 = idx - c*242;
            int row = r2 / 11, u = r2 - row*11;
            const unsigned int* src = (const unsigned int*)
                (xb + (size_t)c*HWX + (size_t)(gy0+row)*WW + gx0);
            *(unsigned int*)&win[c][row][2*u] = src[u];
        }
    } else {
        for (int idx = k; idx < 3*22*22; idx += 256) {
            int c = idx / 484, r2 = idx - c*484;
            int row = r2 / 22, col = r2 - row*22;
            int gy = min(max(gy0+row, 0), HH-1);
            int gx = min(max(gx0+col, 0), WW-1);
            win[c][row][col] = xb[(size_t)c*HWX + (size_t)gy*WW + gx];
        }
    }
    __syncthreads();

    unsigned int d2 = offu[(size_t)p*KPTS + k];
    float dy = __uint_as_float((d2 & 0xffffu) << 16);
    float dx = __uint_as_float(d2 & 0xffff0000u);
    float py = (float)(ho*PATCH + (k >> 4)) + dy;
    float px = (float)(wo*PATCH + (k & 15)) + dx;
    float fy = floorf(py), fx = floorf(px);
    float wy1 = py - fy, wx1 = px - fx;
    float wy0 = 1.f - wy1, wx0 = 1.f - wx1;
    int y0 = (int)fy, x0 = (int)fx;
    int y1 = y0 + 1, x1 = x0 + 1;
    bool oky0 = (y0 >= 0) & (y0 < HH);
    bool oky1 = (y1 >= 0) & (y1 < HH);
    bool okx0 = (x0 >= 0) & (x0 < WW);
    bool okx1 = (x1 >= 0) & (x1 < WW);
    float w00 = wy0*wx0, w01 = wy0*wx1, w10 = wy1*wx0, w11 = wy1*wx1;

    int ry = y0 - gy0, rx = x0 - gx0;
    if (ry >= 0 && ry <= 20 && rx >= 0 && rx <= 20) {
        float m00 = oky0 && okx0 ? 1.f : 0.f;
        float m01 = oky0 && okx1 ? 1.f : 0.f;
        float m10 = oky1 && okx0 ? 1.f : 0.f;
        float m11 = oky1 && okx1 ? 1.f : 0.f;
#pragma unroll
        for (int c = 0; c < CIN; ++c) {
            float v00 = bf2f(win[c][ry  ][rx  ]) * m00;
            float v01 = bf2f(win[c][ry  ][rx+1]) * m01;
            float v10 = bf2f(win[c][ry+1][rx  ]) * m10;
            float v11 = bf2f(win[c][ry+1][rx+1]) * m11;
            float v = v00*w00 + v01*w01 + v10*w10 + v11*w11;
            A2[(size_t)p*KDIM + c*KPTS + k] = f2bf(v);
        }
    } else {
        int yc0 = min(max(y0, 0), HH-1), yc1 = min(max(y1, 0), HH-1);
        int xc0 = min(max(x0, 0), WW-1), xc1 = min(max(x1, 0), WW-1);
#pragma unroll
        for (int c = 0; c < CIN; ++c) {
            const unsigned short* xc = xb + (size_t)c*HWX;
            float v00 = (oky0 && okx0) ? bf2f(xc[(size_t)yc0*WW + xc0]) : 0.f;
            float v01 = (oky0 && okx1) ? bf2f(xc[(size_t)yc0*WW + xc1]) : 0.f;
            float v10 = (oky1 && okx0) ? bf2f(xc[(size_t)yc1*WW + xc0]) : 0.f;
            float v11 = (oky1 && okx1) ? bf2f(xc[(size_t)yc1*WW + xc1]) : 0.f;
            float v = v00*w00 + v01*w01 + v10*w10 + v11*w11;
            A2[(size_t)p*KDIM + c*KPTS + k] = f2bf(v);
        }
    }
}

// ---------------------------------------------------------------------------
// GEMM2 [exact R15]: 8-phase 256x256 ring, single barrier per phase,
// counted vmcnt(4), fused BN partials.
// ---------------------------------------------------------------------------
__global__ __launch_bounds__(512) void gemm_deform(
    const unsigned short* __restrict__ A, const unsigned short* __restrict__ Bw,
    unsigned short* __restrict__ Cbf, float* __restrict__ psum, float* __restrict__ psq)
{
    __shared__ unsigned short lds[4*16384];   // 131072 B
    const int t = threadIdx.x;
    const int lane = t & 63;
    const int w = t >> 6;
    const int wr = w >> 2, wc = w & 3;

    int bid = blockIdx.x;                     // 147 = 3*19 + 5*18
    int xcd = bid & 7, jj = bid >> 3;
    int idx = (xcd < 3) ? xcd*19 + jj : 57 + (xcd-3)*18 + jj;
    const int mblk = idx / 3;
    const int bm = mblk*256, bn = (idx % 3)*256;

    const int schunk = ((t & 3) ^ ((t >> 3) & 3)) << 3;
    const unsigned short* aSrc = A  + (size_t)(bm + (t >> 2))*KDIM + schunk;
    const unsigned short* bSrc = Bw + (size_t)(bn + (t >> 2))*KDIM + schunk;

#define STG_A(s, k0) do { \
        unsigned short* d = lds + (s)*16384 + t*8; \
        GLOAD16(aSrc + (k0), d); \
        GLOAD16(aSrc + (size_t)128*KDIM + (k0), d + 4096); } while(0)
#define STG_B(s, k0) do { \
        unsigned short* d = lds + (s)*16384 + 8192 + t*8; \
        GLOAD16(bSrc + (k0), d); \
        GLOAD16(bSrc + (size_t)128*KDIM + (k0), d + 4096); } while(0)

    const int klocs = (((lane >> 4) ^ ((lane >> 1) & 3)) << 3);
    const int arow0 = wr*128 + (lane & 15);
    const int brow0 = wc*64  + (lane & 15);

    f32x4 acc[8][4] = {};

    STG_A(0, 0);  STG_B(0, 0);
    STG_A(1, 32); STG_B(1, 32);
    asm volatile("s_waitcnt vmcnt(4)" ::: "memory");
    __builtin_amdgcn_s_barrier();

    short8 af[8], bv[4];
    for (int kt = 0; kt < 12; ++kt) {
        const int s0 = (2*kt) & 3;
        const int s1 = s0 + 1;
        const int s2 = (s0 + 2) & 3;
        const int s3 = (s0 + 3) & 3;
        const int k2 = (2*kt + 2) * 32;
        const int k3 = (2*kt + 3) * 32;
        const unsigned short* H0 = lds + s0*16384;
        const unsigned short* H1 = lds + s1*16384;

        // ---- phase 0
#pragma unroll
        for (int m = 0; m < 8; ++m) af[m] = *(const short8*)&H0[(arow0 + m*16)*32 + klocs];
        bv[0] = *(const short8*)&H0[8192 + (brow0 +  0)*32 + klocs];
        bv[1] = *(const short8*)&H0[8192 + (brow0 + 16)*32 + klocs];
        if (kt < 11) STG_A(s2, k2);
        __builtin_amdgcn_s_barrier();
        asm volatile("s_waitcnt lgkmcnt(0)" ::: "memory");
        __builtin_amdgcn_s_setprio(1);
#pragma unroll
        for (int m = 0; m < 8; ++m) {
            acc[m][0] = __builtin_amdgcn_mfma_f32_16x16x32_bf16(af[m], bv[0], acc[m][0], 0, 0, 0);
            acc[m][1] = __builtin_amdgcn_mfma_f32_16x16x32_bf16(af[m], bv[1], acc[m][1], 0, 0, 0);
        }
        __builtin_amdgcn_s_setprio(0);

        // ---- phase 1
        bv[2] = *(const short8*)&H0[8192 + (brow0 + 32)*32 + klocs];
        bv[3] = *(const short8*)&H0[8192 + (brow0 + 48)*32 + klocs];
        if (kt < 11) { STG_B(s2, k2);
            asm volatile("s_waitcnt vmcnt(4)" ::: "memory");
        } else {
            asm volatile("s_waitcnt vmcnt(0)" ::: "memory");
        }
        __builtin_amdgcn_s_barrier();
        asm volatile("s_waitcnt lgkmcnt(0)" ::: "memory");
        __builtin_amdgcn_s_setprio(1);
#pragma unroll
        for (int m = 0; m < 8; ++m) {
            acc[m][2] = __builtin_amdgcn_mfma_f32_16x16x32_bf16(af[m], bv[2], acc[m][2], 0, 0, 0);
            acc[m][3] = __builtin_amdgcn_mfma_f32_16x16x32_bf16(af[m], bv[3], acc[m][3], 0, 0, 0);
        }
        __builtin_amdgcn_s_setprio(0);

        // ---- phase 2
#pragma unroll
        for (int m = 0; m < 8; ++m) af[m] = *(const short8*)&H1[(arow0 + m*16)*32 + klocs];
        bv[0] = *(const short8*)&H1[8192 + (brow0 +  0)*32 + klocs];
        bv[1] = *(const short8*)&H1[8192 + (brow0 + 16)*32 + klocs];
        if (kt < 11) STG_A(s3, k3);
        __builtin_amdgcn_s_barrier();
        asm volatile("s_waitcnt lgkmcnt(0)" ::: "memory");
        __builtin_amdgcn_s_setprio(1);
#pragma unroll
        for (int m = 0; m < 8; ++m) {
            acc[m][0] = __builtin_amdgcn_mfma_f32_16x16x32_bf16(af[m], bv[0], acc[m][0], 0, 0, 0);
            acc[m][1] = __builtin_amdgcn_mfma_f32_16x16x32_bf16(af[m], bv[1], acc[m][1], 0, 0, 0);
        }
        __builtin_amdgcn_s_setprio(0);

        // ---- phase 3
        bv[2] = *(const short8*)&H1[8192 + (brow0 + 32)*32 + klocs];
        bv[3] = *(const short8*)&H1[8192 + (brow0 + 48)*32 + klocs];
        if (kt < 11) { STG_B(s3, k3);
            asm volatile("s_waitcnt vmcnt(4)" ::: "memory");
        }
        __builtin_amdgcn_s_barrier();
        asm volatile("s_waitcnt lgkmcnt(0)" ::: "memory");
        __builtin_amdgcn_s_setprio(1);
#pragma unroll
        for (int m = 0; m < 8; ++m) {
            acc[m][2] = __builtin_amdgcn_mfma_f32_16x16x32_bf16(af[m], bv[2], acc[m][2], 0, 0, 0);
            acc[m][3] = __builtin_amdgcn_mfma_f32_16x16x32_bf16(af[m], bv[3], acc[m][3], 0, 0, 0);
        }
        __builtin_amdgcn_s_setprio(0);
    }
#undef STG_A
#undef STG_B

    asm volatile("s_waitcnt lgkmcnt(0)" ::: "memory");

    float s[4] = {}, q[4] = {};
#pragma unroll
    for (int m = 0; m < 8; ++m)
#pragma unroll
        for (int n = 0; n < 4; ++n)
#pragma unroll
            for (int r = 0; r < 4; ++r) {
                float v = acc[m][n][r];
                s[n] += v; q[n] += v*v;
            }
#pragma unroll
    for (int n = 0; n < 4; ++n) {
        s[n] += __shfl_xor(s[n], 16); q[n] += __shfl_xor(q[n], 16);
        s[n] += __shfl_xor(s[n], 32); q[n] += __shfl_xor(q[n], 32);
    }

    __syncthreads();
    float* redS = (float*)lds;        // [2][256]
    float* redQ = redS + 512;
    if (lane < 16) {
#pragma unroll
        for (int n = 0; n < 4; ++n) {
            redS[wr*256 + wc*64 + n*16 + lane] = s[n];
            redQ[wr*256 + wc*64 + n*16 + lane] = q[n];
        }
    }
    __syncthreads();

    const int col0 = bn + wc*64 + (lane & 15);
    const int r0 = (lane >> 4) * 4;
#pragma unroll
    for (int m = 0; m < 8; ++m) {
        int grow = bm + wr*128 + m*16 + r0;
#pragma unroll
        for (int n = 0; n < 4; ++n) {
            int gcol = col0 + n*16;
#pragma unroll
            for (int r = 0; r < 4; ++r)
                Cbf[(size_t)(grow + r)*NOUT + gcol] = f2bf(acc[m][n][r]);
        }
    }
    {
        int half = t >> 8;
        int c = t & 255;
        psum[(size_t)(bm/128 + half)*NOUT + bn + c] = redS[half*256 + c];
        psq [(size_t)(bm/128 + half)*NOUT + bn + c] = redQ[half*256 + c];
    }
}

// ---------------------------------------------------------------------------
__global__ __launch_bounds__(256) void bn_final(
    const float* __restrict__ psum, const float* __restrict__ psq,
    const float* __restrict__ gamma, const float* __restrict__ beta,
    float* __restrict__ scale, float* __restrict__ shift)
{
    int o = blockIdx.x*256 + threadIdx.x;
    float s = 0.f, q = 0.f;
    for (int i = 0; i < NRB; ++i) {
        s += psum[(size_t)i*NOUT + o];
        q += psq [(size_t)i*NOUT + o];
    }
    float mean = s * (1.0f/(float)NPATCH);
    float var  = q * (1.0f/(float)NPATCH) - mean*mean;
    float inv  = 1.0f / sqrtf(var + EPSF);
    float sc   = gamma[o] * inv;
    scale[o] = sc;
    shift[o] = beta[o] - mean*sc;
}

// ---------------------------------------------------------------------------
__global__ __launch_bounds__(256) void norm_gelu(
    const unsigned short* __restrict__ ybf, float* __restrict__ out,
    const float* __restrict__ scale, const float* __restrict__ shift)
{
    __shared__ float ssc[NOUT], ssh[NOUT];
    for (int i = threadIdx.x; i < NOUT; i += 256) { ssc[i] = scale[i]; ssh[i] = shift[i]; }
    __syncthreads();
    const size_t total8 = (size_t)NPATCH * NOUT / 8;
    for (size_t i = (size_t)blockIdx.x*256 + threadIdx.x; i < total8;
         i += (size_t)gridDim.x*256) {
        uint4 v = ((const uint4*)ybf)[i];
        int og = (int)(i % (NOUT/8)) * 8;
        float4 o0, o1;
        o0.x = gelu_exact(__uint_as_float(v.x << 16)        * ssc[og+0] + ssh[og+0]);
        o0.y = gelu_exact(__uint_as_float(v.x & 0xffff0000u)* ssc[og+1] + ssh[og+1]);
        o0.z = gelu_exact(__uint_as_float(v.y << 16)        * ssc[og+2] + ssh[og+2]);
        o0.w = gelu_exact(__uint_as_float(v.y & 0xffff0000u)* ssc[og+3] + ssh[og+3]);
        o1.x = gelu_exact(__uint_as_float(v.z << 16)        * ssc[og+4] + ssh[og+4]);
        o1.y = gelu_exact(__uint_as_float(v.z & 0xffff0000u)* ssc[og+5] + ssh[og+5]);
        o1.z = gelu_exact(__uint_as_float(v.w << 16)        * ssc[og+6] + ssh[og+6]);
        o1.w = gelu_exact(__uint_as_float(v.w & 0xffff0000u)* ssc[og+7] + ssh[og+7]);
        ((float4*)out)[2*i]   = o0;
        ((float4*)out)[2*i+1] = o1;
    }
}

// ---------------------------------------------------------------------------
extern "C" void kernel_launch(void* const* d_in, const int* in_sizes, int n_in,
                              void* d_out, int out_size, void* d_ws, size_t ws_size,
                              hipStream_t stream)
{
    const float* x      = (const float*)d_in[0];
    const float* offw   = (const float*)d_in[1];
    const float* offb   = (const float*)d_in[2];
    const float* dconvw = (const float*)d_in[3];
    const float* gamma  = (const float*)d_in[4];
    const float* beta   = (const float*)d_in[5];
    float* out = (float*)d_out;

    const size_t NX  = (size_t)BATCH*CHW;
    const size_t NW1 = (size_t)NOFF*KDIM;
    const size_t NW2 = (size_t)NOUT*KDIM;

    unsigned short* xbf   = (unsigned short*)d_ws;
    unsigned short* wbf1  = xbf  + NX;
    unsigned short* wbf2  = wbf1 + NW1;
    unsigned short* A2    = wbf2 + NW2;
    unsigned short* off   = A2   + (size_t)NPATCH*KDIM;
    unsigned short* ybf   = off  + (size_t)NPATCH*NOFF;
    float* fscratch = (float*)(ybf + (size_t)NPATCH*NOUT);
    float* psum  = fscratch;
    float* psq   = psum + NRB*NOUT;
    float* scale = psq  + NRB*NOUT;
    float* shift = scale + NOUT;

    cvt_all<<<4096, 256, 0, stream>>>(x, offw, dconvw, xbf, wbf1, wbf2);
    gemm_offsets<<<392, 256, 0, stream>>>(xbf, wbf1, offb, off);
    sampler<<<NPATCH, 256, 0, stream>>>(xbf, (const unsigned int*)off, A2);
    gemm_deform<<<147, 512, 0, stream>>>(A2, wbf2, ybf, psum, psq);
    bn_final<<<3, 256, 0, stream>>>(psum, psq, gamma, beta, scale, shift);
    norm_gelu<<<2048, 256, 0, stream>>>(ybf, out, scale, shift);
}

// Round 19
// 99.776 us; speedup vs baseline: 1.6449x; 1.0036x over previous
//
#include <hip/hip_runtime.h>
#include <math.h>

#define PATCH 16
#define BATCH 64
#define CIN 3
#define HH 224
#define WW 224
#define NPATCH (BATCH*14*14)       // 12544
#define KDIM 768
#define NOFF 512
#define NOUT 768
#define KPTS 256
#define EPSF 1e-5f
#define CHW (CIN*HH*WW)            // 150528
#define HWX (HH*WW)                // 50176
#define NRB (NPATCH/128)           // 98

using short8 = __attribute__((ext_vector_type(8))) short;
using f32x4  = __attribute__((ext_vector_type(4))) float;

#define GLOAD16(g, l) __builtin_amdgcn_global_load_lds( \
    (const __attribute__((address_space(1))) void*)(g), \
    (__attribute__((address_space(3))) void*)(l), 16, 0, 0)

__device__ __forceinline__ unsigned short f2bf(float f) {
    unsigned int u = __float_as_uint(f);
    u = (u + 0x7fffu + ((u >> 16) & 1u)) >> 16;   // RNE
    return (unsigned short)u;
}
__device__ __forceinline__ float bf2f(unsigned short h) {
    return __uint_as_float(((unsigned int)h) << 16);
}
__device__ __forceinline__ float gelu_exact(float v) {
    return 0.5f * v * (1.0f + erff(v * 0.70710678118654752440f));
}

// ---------------------------------------------------------------------------
// fused fp32 -> bf16 bulk convert for x, offw, dconvw (one launch) [R18]
// ---------------------------------------------------------------------------
#define N4X (BATCH*CHW/4)
#define N4W1 (NOFF*KDIM/4)
#define N4W2 (NOUT*KDIM/4)
#define N4ALL (N4X+N4W1+N4W2)

__global__ __launch_bounds__(256) void cvt_all(
    const float* __restrict__ x, const float* __restrict__ w1,
    const float* __restrict__ w2, unsigned short* __restrict__ xbf,
    unsigned short* __restrict__ wbf1, unsigned short* __restrict__ wbf2)
{
    for (int i = blockIdx.x*256 + threadIdx.x; i < N4ALL; i += gridDim.x*256) {
        const float* src; unsigned short* dst; int j;
        if (i < N4X)            { src = x;  dst = xbf;  j = i; }
        else if (i < N4X+N4W1)  { src = w1; dst = wbf1; j = i - N4X; }
        else                    { src = w2; dst = wbf2; j = i - N4X - N4W1; }
        float4 v = ((const float4*)src)[j];
        ((ushort4*)dst)[j] = make_ushort4(f2bf(v.x), f2bf(v.y), f2bf(v.z), f2bf(v.w));
    }
}

// ---------------------------------------------------------------------------
// GEMM1 [exact R18]: single barrier/iter, 5-slot ring, depth-3
// ---------------------------------------------------------------------------
__global__ __launch_bounds__(256) void gemm_offsets(
    const unsigned short* __restrict__ xbf, const unsigned short* __restrict__ Bw,
    const float* __restrict__ offb, unsigned short* __restrict__ off)
{
    __shared__ unsigned short lds[5*8192];
    const int t = threadIdx.x;
    const int lane = t & 63;
    const int w = t >> 6, wr = w >> 1, wc = w & 1;

    int bid = blockIdx.x;                       // 392 = 8*49
    int idx = (bid & 7)*49 + (bid >> 3);
    const int bm = (idx >> 2) * 128, bn = (idx & 3) * 128;

    const int rq = t >> 2;
    const int ksw = (((t & 3) ^ ((t >> 3) & 3)) << 3);

    const unsigned short* aBase0;
    const unsigned short* aBase1;
    {
        int p0 = bm + rq,      b0 = p0/196, r0 = p0%196;
        int p1 = bm + 64 + rq, b1 = p1/196, r1 = p1%196;
        aBase0 = xbf + (size_t)b0*CHW + (size_t)((r0/14)*PATCH)*WW + (size_t)((r0%14)*PATCH);
        aBase1 = xbf + (size_t)b1*CHW + (size_t)((r1/14)*PATCH)*WW + (size_t)((r1%14)*PATCH);
    }
    const unsigned short* bS0 = Bw + (size_t)(bn + rq)*KDIM + ksw;
    const unsigned short* bS1 = Bw + (size_t)(bn + 64 + rq)*KDIM + ksw;

    const int row_a = wr*64 + (lane & 15);
    const int row_b = wc*64 + (lane & 15);
    const int klocs = (((lane >> 4) ^ ((lane >> 1) & 3)) << 3);

#define STG1(slot, k0) do { \
        unsigned short* d = lds + (slot)*8192 + t*8; \
        int e = (k0) + ksw; \
        size_t xo = (size_t)(e >> 8)*HWX + (size_t)((e >> 4) & 15)*WW + (e & 15); \
        GLOAD16(aBase0 + xo, d); \
        GLOAD16(aBase1 + xo, d + 2048); \
        GLOAD16(bS0 + (k0), d + 4096); \
        GLOAD16(bS1 + (k0), d + 6144); \
    } while(0)

    f32x4 acc[4][4] = {};
    STG1(0, 0); STG1(1, 32); STG1(2, 64);
    asm volatile("s_waitcnt vmcnt(8)" ::: "memory");
    __builtin_amdgcn_s_barrier();
#pragma unroll
    for (int it = 0; it < 24; ++it) {
        const unsigned short* As_ = lds + (it%5)*8192;
        const unsigned short* Bs_ = As_ + 4096;
        short8 af[4], bv[4];
#pragma unroll
        for (int m = 0; m < 4; ++m) af[m] = *(const short8*)&As_[(row_a + m*16)*32 + klocs];
#pragma unroll
        for (int n = 0; n < 4; ++n) bv[n] = *(const short8*)&Bs_[(row_b + n*16)*32 + klocs];
        if (it + 3 < 24) STG1((it+3)%5, (it+3)*32);
        if (it < 23) {
            if (it <= 20)      asm volatile("s_waitcnt vmcnt(8)" ::: "memory");
            else if (it == 21) asm volatile("s_waitcnt vmcnt(4)" ::: "memory");
            else               asm volatile("s_waitcnt vmcnt(0)" ::: "memory");
            __builtin_amdgcn_s_barrier();
        }
        asm volatile("s_waitcnt lgkmcnt(0)" ::: "memory");
        __builtin_amdgcn_s_setprio(1);
#pragma unroll
        for (int m = 0; m < 4; ++m)
#pragma unroll
            for (int n = 0; n < 4; ++n)
                acc[m][n] = __builtin_amdgcn_mfma_f32_16x16x32_bf16(af[m], bv[n], acc[m][n], 0, 0, 0);
        __builtin_amdgcn_s_setprio(0);
    }
#undef STG1

    const int col0 = bn + wc*64 + (lane & 15);
    const int r0 = (lane >> 4) * 4;
#pragma unroll
    for (int m = 0; m < 4; ++m) {
        int grow = bm + wr*64 + m*16 + r0;
#pragma unroll
        for (int n = 0; n < 4; ++n) {
            int gcol = col0 + n*16;
            float bias = offb[gcol];
#pragma unroll
            for (int r = 0; r < 4; ++r)
                off[(size_t)(grow + r)*NOFF + gcol] = f2bf(acc[m][n][r] + bias);
        }
    }
}

// ---------------------------------------------------------------------------
// Sampler [exact R18]: LDS-staged 22x22 bf16 window; exact global fallback
// ---------------------------------------------------------------------------
__global__ __launch_bounds__(256) void sampler(
    const unsigned short* __restrict__ xbf, const unsigned int* __restrict__ offu,
    unsigned short* __restrict__ A2)
{
    __shared__ unsigned short win[3][22][24];
    int p = blockIdx.x;
    int k = threadIdx.x;
    int b = p / 196, rem = p % 196;
    int ho = rem / 14, wo = rem % 14;
    const int gy0 = ho*PATCH - 2, gx0 = wo*PATCH - 2;
    const unsigned short* xb = xbf + (size_t)b*CHW;

    bool interior = (ho >= 1) && (ho <= 12) && (wo >= 1) && (wo <= 12);
    if (interior) {
        for (int idx = k; idx < 3*22*11; idx += 256) {
            int c = idx / 242, r2 = idx - c*242;
            int row = r2 / 11, u = r2 - row*11;
            const unsigned int* src = (const unsigned int*)
                (xb + (size_t)c*HWX + (size_t)(gy0+row)*WW + gx0);
            *(unsigned int*)&win[c][row][2*u] = src[u];
        }
    } else {
        for (int idx = k; idx < 3*22*22; idx += 256) {
            int c = idx / 484, r2 = idx - c*484;
            int row = r2 / 22, col = r2 - row*22;
            int gy = min(max(gy0+row, 0), HH-1);
            int gx = min(max(gx0+col, 0), WW-1);
            win[c][row][col] = xb[(size_t)c*HWX + (size_t)gy*WW + gx];
        }
    }
    __syncthreads();

    unsigned int d2 = offu[(size_t)p*KPTS + k];
    float dy = __uint_as_float((d2 & 0xffffu) << 16);
    float dx = __uint_as_float(d2 & 0xffff0000u);
    float py = (float)(ho*PATCH + (k >> 4)) + dy;
    float px = (float)(wo*PATCH + (k & 15)) + dx;
    float fy = floorf(py), fx = floorf(px);
    float wy1 = py - fy, wx1 = px - fx;
    float wy0 = 1.f - wy1, wx0 = 1.f - wx1;
    int y0 = (int)fy, x0 = (int)fx;
    int y1 = y0 + 1, x1 = x0 + 1;
    bool oky0 = (y0 >= 0) & (y0 < HH);
    bool oky1 = (y1 >= 0) & (y1 < HH);
    bool okx0 = (x0 >= 0) & (x0 < WW);
    bool okx1 = (x1 >= 0) & (x1 < WW);
    float w00 = wy0*wx0, w01 = wy0*wx1, w10 = wy1*wx0, w11 = wy1*wx1;

    int ry = y0 - gy0, rx = x0 - gx0;
    if (ry >= 0 && ry <= 20 && rx >= 0 && rx <= 20) {
        float m00 = oky0 && okx0 ? 1.f : 0.f;
        float m01 = oky0 && okx1 ? 1.f : 0.f;
        float m10 = oky1 && okx0 ? 1.f : 0.f;
        float m11 = oky1 && okx1 ? 1.f : 0.f;
#pragma unroll
        for (int c = 0; c < CIN; ++c) {
            float v00 = bf2f(win[c][ry  ][rx  ]) * m00;
            float v01 = bf2f(win[c][ry  ][rx+1]) * m01;
            float v10 = bf2f(win[c][ry+1][rx  ]) * m10;
            float v11 = bf2f(win[c][ry+1][rx+1]) * m11;
            float v = v00*w00 + v01*w01 + v10*w10 + v11*w11;
            A2[(size_t)p*KDIM + c*KPTS + k] = f2bf(v);
        }
    } else {
        int yc0 = min(max(y0, 0), HH-1), yc1 = min(max(y1, 0), HH-1);
        int xc0 = min(max(x0, 0), WW-1), xc1 = min(max(x1, 0), WW-1);
#pragma unroll
        for (int c = 0; c < CIN; ++c) {
            const unsigned short* xc = xb + (size_t)c*HWX;
            float v00 = (oky0 && okx0) ? bf2f(xc[(size_t)yc0*WW + xc0]) : 0.f;
            float v01 = (oky0 && okx1) ? bf2f(xc[(size_t)yc0*WW + xc1]) : 0.f;
            float v10 = (oky1 && okx0) ? bf2f(xc[(size_t)yc1*WW + xc0]) : 0.f;
            float v11 = (oky1 && okx1) ? bf2f(xc[(size_t)yc1*WW + xc1]) : 0.f;
            float v = v00*w00 + v01*w01 + v10*w10 + v11*w11;
            A2[(size_t)p*KDIM + c*KPTS + k] = f2bf(v);
        }
    }
}

// ---------------------------------------------------------------------------
// GEMM2 [exact R18/R15]: 8-phase 256x256 ring, single barrier per phase,
// counted vmcnt(4), fused BN partials.
// ---------------------------------------------------------------------------
__global__ __launch_bounds__(512) void gemm_deform(
    const unsigned short* __restrict__ A, const unsigned short* __restrict__ Bw,
    unsigned short* __restrict__ Cbf, float* __restrict__ psum, float* __restrict__ psq)
{
    __shared__ unsigned short lds[4*16384];   // 131072 B
    const int t = threadIdx.x;
    const int lane = t & 63;
    const int w = t >> 6;
    const int wr = w >> 2, wc = w & 3;

    int bid = blockIdx.x;                     // 147 = 3*19 + 5*18
    int xcd = bid & 7, jj = bid >> 3;
    int idx = (xcd < 3) ? xcd*19 + jj : 57 + (xcd-3)*18 + jj;
    const int mblk = idx / 3;
    const int bm = mblk*256, bn = (idx % 3)*256;

    const int schunk = ((t & 3) ^ ((t >> 3) & 3)) << 3;
    const unsigned short* aSrc = A  + (size_t)(bm + (t >> 2))*KDIM + schunk;
    const unsigned short* bSrc = Bw + (size_t)(bn + (t >> 2))*KDIM + schunk;

#define STG_A(s, k0) do { \
        unsigned short* d = lds + (s)*16384 + t*8; \
        GLOAD16(aSrc + (k0), d); \
        GLOAD16(aSrc + (size_t)128*KDIM + (k0), d + 4096); } while(0)
#define STG_B(s, k0) do { \
        unsigned short* d = lds + (s)*16384 + 8192 + t*8; \
        GLOAD16(bSrc + (k0), d); \
        GLOAD16(bSrc + (size_t)128*KDIM + (k0), d + 4096); } while(0)

    const int klocs = (((lane >> 4) ^ ((lane >> 1) & 3)) << 3);
    const int arow0 = wr*128 + (lane & 15);
    const int brow0 = wc*64  + (lane & 15);

    f32x4 acc[8][4] = {};

    STG_A(0, 0);  STG_B(0, 0);
    STG_A(1, 32); STG_B(1, 32);
    asm volatile("s_waitcnt vmcnt(4)" ::: "memory");
    __builtin_amdgcn_s_barrier();

    short8 af[8], bv[4];
    for (int kt = 0; kt < 12; ++kt) {
        const int s0 = (2*kt) & 3;
        const int s1 = s0 + 1;
        const int s2 = (s0 + 2) & 3;
        const int s3 = (s0 + 3) & 3;
        const int k2 = (2*kt + 2) * 32;
        const int k3 = (2*kt + 3) * 32;
        const unsigned short* H0 = lds + s0*16384;
        const unsigned short* H1 = lds + s1*16384;

        // ---- phase 0
#pragma unroll
        for (int m = 0; m < 8; ++m) af[m] = *(const short8*)&H0[(arow0 + m*16)*32 + klocs];
        bv[0] = *(const short8*)&H0[8192 + (brow0 +  0)*32 + klocs];
        bv[1] = *(const short8*)&H0[8192 + (brow0 + 16)*32 + klocs];
        if (kt < 11) STG_A(s2, k2);
        __builtin_amdgcn_s_barrier();
        asm volatile("s_waitcnt lgkmcnt(0)" ::: "memory");
        __builtin_amdgcn_s_setprio(1);
#pragma unroll
        for (int m = 0; m < 8; ++m) {
            acc[m][0] = __builtin_amdgcn_mfma_f32_16x16x32_bf16(af[m], bv[0], acc[m][0], 0, 0, 0);
            acc[m][1] = __builtin_amdgcn_mfma_f32_16x16x32_bf16(af[m], bv[1], acc[m][1], 0, 0, 0);
        }
        __builtin_amdgcn_s_setprio(0);

        // ---- phase 1
        bv[2] = *(const short8*)&H0[8192 + (brow0 + 32)*32 + klocs];
        bv[3] = *(const short8*)&H0[8192 + (brow0 + 48)*32 + klocs];
        if (kt < 11) { STG_B(s2, k2);
            asm volatile("s_waitcnt vmcnt(4)" ::: "memory");
        } else {
            asm volatile("s_waitcnt vmcnt(0)" ::: "memory");
        }
        __builtin_amdgcn_s_barrier();
        asm volatile("s_waitcnt lgkmcnt(0)" ::: "memory");
        __builtin_amdgcn_s_setprio(1);
#pragma unroll
        for (int m = 0; m < 8; ++m) {
            acc[m][2] = __builtin_amdgcn_mfma_f32_16x16x32_bf16(af[m], bv[2], acc[m][2], 0, 0, 0);
            acc[m][3] = __builtin_amdgcn_mfma_f32_16x16x32_bf16(af[m], bv[3], acc[m][3], 0, 0, 0);
        }
        __builtin_amdgcn_s_setprio(0);

        // ---- phase 2
#pragma unroll
        for (int m = 0; m < 8; ++m) af[m] = *(const short8*)&H1[(arow0 + m*16)*32 + klocs];
        bv[0] = *(const short8*)&H1[8192 + (brow0 +  0)*32 + klocs];
        bv[1] = *(const short8*)&H1[8192 + (brow0 + 16)*32 + klocs];
        if (kt < 11) STG_A(s3, k3);
        __builtin_amdgcn_s_barrier();
        asm volatile("s_waitcnt lgkmcnt(0)" ::: "memory");
        __builtin_amdgcn_s_setprio(1);
#pragma unroll
        for (int m = 0; m < 8; ++m) {
            acc[m][0] = __builtin_amdgcn_mfma_f32_16x16x32_bf16(af[m], bv[0], acc[m][0], 0, 0, 0);
            acc[m][1] = __builtin_amdgcn_mfma_f32_16x16x32_bf16(af[m], bv[1], acc[m][1], 0, 0, 0);
        }
        __builtin_amdgcn_s_setprio(0);

        // ---- phase 3
        bv[2] = *(const short8*)&H1[8192 + (brow0 + 32)*32 + klocs];
        bv[3] = *(const short8*)&H1[8192 + (brow0 + 48)*32 + klocs];
        if (kt < 11) { STG_B(s3, k3);
            asm volatile("s_waitcnt vmcnt(4)" ::: "memory");
        }
        __builtin_amdgcn_s_barrier();
        asm volatile("s_waitcnt lgkmcnt(0)" ::: "memory");
        __builtin_amdgcn_s_setprio(1);
#pragma unroll
        for (int m = 0; m < 8; ++m) {
            acc[m][2] = __builtin_amdgcn_mfma_f32_16x16x32_bf16(af[m], bv[2], acc[m][2], 0, 0, 0);
            acc[m][3] = __builtin_amdgcn_mfma_f32_16x16x32_bf16(af[m], bv[3], acc[m][3], 0, 0, 0);
        }
        __builtin_amdgcn_s_setprio(0);
    }
#undef STG_A
#undef STG_B

    asm volatile("s_waitcnt lgkmcnt(0)" ::: "memory");

    float s[4] = {}, q[4] = {};
#pragma unroll
    for (int m = 0; m < 8; ++m)
#pragma unroll
        for (int n = 0; n < 4; ++n)
#pragma unroll
            for (int r = 0; r < 4; ++r) {
                float v = acc[m][n][r];
                s[n] += v; q[n] += v*v;
            }
#pragma unroll
    for (int n = 0; n < 4; ++n) {
        s[n] += __shfl_xor(s[n], 16); q[n] += __shfl_xor(q[n], 16);
        s[n] += __shfl_xor(s[n], 32); q[n] += __shfl_xor(q[n], 32);
    }

    __syncthreads();
    float* redS = (float*)lds;        // [2][256]
    float* redQ = redS + 512;
    if (lane < 16) {
#pragma unroll
        for (int n = 0; n < 4; ++n) {
            redS[wr*256 + wc*64 + n*16 + lane] = s[n];
            redQ[wr*256 + wc*64 + n*16 + lane] = q[n];
        }
    }
    __syncthreads();

    const int col0 = bn + wc*64 + (lane & 15);
    const int r0 = (lane >> 4) * 4;
#pragma unroll
    for (int m = 0; m < 8; ++m) {
        int grow = bm + wr*128 + m*16 + r0;
#pragma unroll
        for (int n = 0; n < 4; ++n) {
            int gcol = col0 + n*16;
#pragma unroll
            for (int r = 0; r < 4; ++r)
                Cbf[(size_t)(grow + r)*NOUT + gcol] = f2bf(acc[m][n][r]);
        }
    }
    {
        int half = t >> 8;
        int c = t & 255;
        psum[(size_t)(bm/128 + half)*NOUT + bn + c] = redS[half*256 + c];
        psq [(size_t)(bm/128 + half)*NOUT + bn + c] = redQ[half*256 + c];
    }
}

// ---------------------------------------------------------------------------
// norm_gelu — column-panel version with FUSED per-panel BN finalization.
// grid 588 = 196 row-chunks (64 rows) x 3 panels (256 cols); each block:
//   1) scale/shift for its 256 cols from the psum/psq table (L2-resident)
//   2) BN+GELU on its 64x256 tile: bf16 y in -> fp32 d_out
// Replaces bn_final + old norm_gelu (one fewer launch).
// ---------------------------------------------------------------------------
__global__ __launch_bounds__(256) void norm_gelu(
    const unsigned short* __restrict__ ybf, float* __restrict__ out,
    const float* __restrict__ psum, const float* __restrict__ psq,
    const float* __restrict__ gamma, const float* __restrict__ beta)
{
    __shared__ float ssc[256], ssh[256];
    const int t = threadIdx.x;
    const int panel = blockIdx.x % 3;
    const int r0 = (blockIdx.x / 3) * 64;
    const int c0 = panel * 256;

    {
        float s = 0.f, q = 0.f;
        for (int i = 0; i < NRB; ++i) {
            s += psum[(size_t)i*NOUT + c0 + t];
            q += psq [(size_t)i*NOUT + c0 + t];
        }
        float mean = s * (1.0f/(float)NPATCH);
        float var  = q * (1.0f/(float)NPATCH) - mean*mean;
        float inv  = 1.0f / sqrtf(var + EPSF);
        float sc   = gamma[c0 + t] * inv;
        ssc[t] = sc;
        ssh[t] = beta[c0 + t] - mean*sc;
    }
    __syncthreads();

    // 64 rows x 32 groups-of-8 = 2048 groups; 8 per thread
#pragma unroll
    for (int k = 0; k < 8; ++k) {
        int g = t + k*256;
        int row = g >> 5, c8 = (g & 31) << 3;
        const unsigned short* src = ybf + (size_t)(r0 + row)*NOUT + c0 + c8;
        float* dst = out + (size_t)(r0 + row)*NOUT + c0 + c8;
        uint4 v = *(const uint4*)src;
        float4 o0, o1;
        o0.x = gelu_exact(__uint_as_float(v.x << 16)        * ssc[c8+0] + ssh[c8+0]);
        o0.y = gelu_exact(__uint_as_float(v.x & 0xffff0000u)* ssc[c8+1] + ssh[c8+1]);
        o0.z = gelu_exact(__uint_as_float(v.y << 16)        * ssc[c8+2] + ssh[c8+2]);
        o0.w = gelu_exact(__uint_as_float(v.y & 0xffff0000u)* ssc[c8+3] + ssh[c8+3]);
        o1.x = gelu_exact(__uint_as_float(v.z << 16)        * ssc[c8+4] + ssh[c8+4]);
        o1.y = gelu_exact(__uint_as_float(v.z & 0xffff0000u)* ssc[c8+5] + ssh[c8+5]);
        o1.z = gelu_exact(__uint_as_float(v.w << 16)        * ssc[c8+6] + ssh[c8+6]);
        o1.w = gelu_exact(__uint_as_float(v.w & 0xffff0000u)* ssc[c8+7] + ssh[c8+7]);
        *(float4*)dst       = o0;
        *(float4*)(dst + 4) = o1;
    }
}

// ---------------------------------------------------------------------------
extern "C" void kernel_launch(void* const* d_in, const int* in_sizes, int n_in,
                              void* d_out, int out_size, void* d_ws, size_t ws_size,
                              hipStream_t stream)
{
    const float* x      = (const float*)d_in[0];
    const float* offw   = (const float*)d_in[1];
    const float* offb   = (const float*)d_in[2];
    const float* dconvw = (const float*)d_in[3];
    const float* gamma  = (const float*)d_in[4];
    const float* beta   = (const float*)d_in[5];
    float* out = (float*)d_out;

    const size_t NX  = (size_t)BATCH*CHW;
    const size_t NW1 = (size_t)NOFF*KDIM;
    const size_t NW2 = (size_t)NOUT*KDIM;

    unsigned short* xbf   = (unsigned short*)d_ws;
    unsigned short* wbf1  = xbf  + NX;
    unsigned short* wbf2  = wbf1 + NW1;
    unsigned short* A2    = wbf2 + NW2;
    unsigned short* off   = A2   + (size_t)NPATCH*KDIM;
    unsigned short* ybf   = off  + (size_t)NPATCH*NOFF;
    float* fscratch = (float*)(ybf + (size_t)NPATCH*NOUT);
    float* psum  = fscratch;
    float* psq   = psum + NRB*NOUT;

    cvt_all<<<4096, 256, 0, stream>>>(x, offw, dconvw, xbf, wbf1, wbf2);
    gemm_offsets<<<392, 256, 0, stream>>>(xbf, wbf1, offb, off);
    sampler<<<NPATCH, 256, 0, stream>>>(xbf, (const unsigned int*)off, A2);
    gemm_deform<<<147, 512, 0, stream>>>(A2, wbf2, ybf, psum, psq);
    norm_gelu<<<588, 256, 0, stream>>>(ybf, out, psum, psq, gamma, beta);
}